// Round 1
// baseline (361.240 us; speedup 1.0000x reference)
//
#include <hip/hip_runtime.h>

// TcEmbedding: x (B=4, S=4096, D=64) f32.
// norms[b,t] = sum_d |x[b,t,d]|
// tc[b,t]   = min{ tau in [1,t] : norms[b,t-tau] < 0.7*(norms[b,t]+1e-8) }, else 0
// Scan backwards from j=t-1: first j with norms[j] < thr gives tau=t-j.

#define DD 64
#define SS 4096
#define TILE 256

// ---------------- Kernel A: L1 norms, one wave (64 lanes) per row ----------
template <typename T>
__global__ void tc_norms_kernel(const float* __restrict__ x,
                                T* __restrict__ norms, int nrows) {
    int gid  = blockIdx.x * blockDim.x + threadIdx.x;
    int row  = gid >> 6;          // one 64-lane wave per row
    int lane = threadIdx.x & 63;
    if (row >= nrows) return;
    T acc = (T)fabsf(x[row * DD + lane]);
    // full-wave butterfly reduce (wave = 64 on gfx950)
    #pragma unroll
    for (int off = 32; off > 0; off >>= 1)
        acc += __shfl_xor(acc, off, 64);
    if (lane == 0) norms[row] = acc;
}

// ---------------- Kernel B: backward scan over LDS-staged norms row --------
template <typename T>
__global__ void tc_scan_kernel(const T* __restrict__ norms,
                               float* __restrict__ out) {
    __shared__ T s[SS];
    // 16 tiles of 256 per batch row (SS/TILE = 16)
    int b    = blockIdx.x >> 4;
    int tile = blockIdx.x & 15;
    const T* row = norms + b * SS;
    for (int i = threadIdx.x; i < SS; i += blockDim.x)
        s[i] = row[i];
    __syncthreads();

    int t  = tile * TILE + (int)threadIdx.x;
    T thr  = (T)0.7 * (s[t] + (T)1e-8);
    int res = 0;
    for (int j = t - 1; j >= 0; --j) {
        if (s[j] < thr) { res = t - j; break; }
    }
    out[b * SS + t] = (float)res;
}

extern "C" void kernel_launch(void* const* d_in, const int* in_sizes, int n_in,
                              void* d_out, int out_size, void* d_ws, size_t ws_size,
                              hipStream_t stream) {
    const float* x = (const float*)d_in[0];
    float* out = (float*)d_out;
    int total = in_sizes[0];          // B*S*D = 1048576
    int nrows = total / DD;           // B*S   = 16384

    int blkA = 256;                               // 4 waves -> 4 rows/block
    int grdA = (nrows * 64 + blkA - 1) / blkA;    // 4096 blocks
    int grdB = nrows / TILE;                      // 64 blocks

    // Prefer double accumulation/compare: a comparison flip near the 0.7
    // threshold changes tc by O(S) >> absmax tolerance. f64 margins ~1e-15.
    if (ws_size >= (size_t)nrows * sizeof(double)) {
        double* nrm = (double*)d_ws;
        tc_norms_kernel<double><<<grdA, blkA, 0, stream>>>(x, nrm, nrows);
        tc_scan_kernel<double><<<grdB, TILE, 0, stream>>>(nrm, out);
    } else {
        float* nrm = (float*)d_ws;
        tc_norms_kernel<float><<<grdA, blkA, 0, stream>>>(x, nrm, nrows);
        tc_scan_kernel<float><<<grdB, TILE, 0, stream>>>(nrm, out);
    }
}

// Round 2
// 100.630 us; speedup vs baseline: 3.5898x; 3.5898x over previous
//
#include <hip/hip_runtime.h>

// TcEmbedding: x (B=4, S=4096, D=64) f32.
// norms[b,t] = sum_d |x[b,t,d]|
// tc[b,t]   = min{ tau in [1,t] : norms[b,t-tau] < 0.7*(norms[b,t]+1e-8) }, else 0
//           = t - j where j is the NEAREST index < t with norms[j] < thr_t.
//
// R2: wave-parallel two-level search. Per row: 64 chunks of 64; per t one wave
// does (a) ballot over partial current chunk, (b) ballot over chunk minima,
// (c) ballot inside the found chunk. ~3 rounds vs ~1300 serial LDS reads (R1
// was 307us at 1.1% VALUBusy: pure dependent-chain latency).

#define DD 64
#define SS 4096
#define NCHUNK 64   // SS / 64

// ---------------- Kernel A: L1 norms, one wave (64 lanes) per row ----------
template <typename T>
__global__ void tc_norms_kernel(const float* __restrict__ x,
                                T* __restrict__ norms, int nrows) {
    int gid  = blockIdx.x * blockDim.x + threadIdx.x;
    int row  = gid >> 6;          // one 64-lane wave per row
    int lane = threadIdx.x & 63;
    if (row >= nrows) return;
    T acc = (T)fabsf(x[row * DD + lane]);
    #pragma unroll
    for (int off = 32; off > 0; off >>= 1)
        acc += __shfl_xor(acc, off, 64);
    if (lane == 0) norms[row] = acc;
}

// ---------------- Kernel B: wave-parallel two-level nearest-below search ---
template <typename T>
__global__ void __launch_bounds__(256)
tc_scan_kernel(const T* __restrict__ norms, float* __restrict__ out) {
    __shared__ T s[SS];
    __shared__ T cmin[NCHUNK];

    int t0    = blockIdx.x * 4;        // 4 t-values per block (1 per wave)
    int b     = t0 >> 12;              // / SS
    int trow0 = t0 & (SS - 1);
    const T* row = norms + b * SS;
    int wave = threadIdx.x >> 6;
    int lane = threadIdx.x & 63;

    // Stage row into LDS; in round r, wave w's 64 lanes cover exactly chunk
    // r*4+w, so a wave min-reduce yields that chunk's minimum for free.
    #pragma unroll
    for (int r = 0; r < SS / 256; ++r) {
        int idx = r * 256 + threadIdx.x;
        T v = row[idx];
        s[idx] = v;
        T m = v;
        #pragma unroll
        for (int off = 32; off > 0; off >>= 1) {
            T o = __shfl_xor(m, off, 64);
            m = (o < m) ? o : m;
        }
        if (lane == 0) cmin[r * 4 + wave] = m;
    }
    __syncthreads();

    int t   = trow0 + wave;            // row-local t for this wave
    T  thr  = (T)0.7 * (s[t] + (T)1e-8);
    int c   = t >> 6;                  // current chunk
    int pos = t & 63;
    int res = 0;

    // (a) partial current chunk: j in [c*64, t)
    T v = s[(c << 6) + lane];
    unsigned long long m = __ballot(lane < pos && v < thr);
    if (m) {                            // wave-uniform branch (m is scalar)
        int j = (c << 6) + (63 - __clzll(m));
        res = t - j;
    } else {
        // (b) which earlier chunk holds a qualifying element? nearest = highest idx
        T cm = cmin[lane];
        unsigned long long mc = __ballot(lane < c && cm < thr);
        if (mc) {
            int cc = 63 - __clzll(mc);
            // (c) locate within that chunk (guaranteed non-empty)
            T v2 = s[(cc << 6) + lane];
            unsigned long long m2 = __ballot(v2 < thr);
            int j = (cc << 6) + (63 - __clzll(m2));
            res = t - j;
        }
    }
    if (lane == 0) out[t0 + wave] = (float)res;
}

extern "C" void kernel_launch(void* const* d_in, const int* in_sizes, int n_in,
                              void* d_out, int out_size, void* d_ws, size_t ws_size,
                              hipStream_t stream) {
    const float* x = (const float*)d_in[0];
    float* out = (float*)d_out;
    int total = in_sizes[0];          // B*S*D = 1048576
    int nrows = total / DD;           // B*S   = 16384

    int blkA = 256;                               // 4 waves -> 4 rows/block
    int grdA = (nrows * 64 + blkA - 1) / blkA;    // 4096 blocks
    int grdB = nrows / 4;                         // 4096 blocks, 1 t per wave

    // Double accumulation/compare: a flip near the 0.7 threshold changes tc
    // by O(S) >> absmax tolerance; f64 margins ~1e-15. (R1: absmax 0.)
    if (ws_size >= (size_t)nrows * sizeof(double)) {
        double* nrm = (double*)d_ws;
        tc_norms_kernel<double><<<grdA, blkA, 0, stream>>>(x, nrm, nrows);
        tc_scan_kernel<double><<<grdB, 256, 0, stream>>>(nrm, out);
    } else {
        float* nrm = (float*)d_ws;
        tc_norms_kernel<float><<<grdA, blkA, 0, stream>>>(x, nrm, nrows);
        tc_scan_kernel<float><<<grdB, 256, 0, stream>>>(nrm, out);
    }
}

// Round 3
// 58.114 us; speedup vs baseline: 6.2161x; 1.7316x over previous
//
#include <hip/hip_runtime.h>

// TcEmbedding: x (B=4, S=4096, D=64) f32.
// norms[b,t] = sum_d |x[b,t,d]|
// tc[b,t]   = t - j, j = nearest index < t with norms[j] < 0.7*(norms[t]+1e-8), else 0.
//
// R3: no LDS staging in the scan. Kernel A computes norms (float4 loads) AND
// per-64-chunk minima once (R2 recomputed the row min-chunks in all 4096
// blocks -> 128MB L2 traffic, 47.9us). Kernel B: per wave, two independent
// L2 loads (current chunk + cmin row) + ballot search; 4 t's per wave.

#define DD 64
#define SS 4096

// ------------- Kernel A: L1 norms + chunk minima, 1 block per 64-row chunk -
template <typename T>
__global__ void __launch_bounds__(256)
tc_norms_cmin_kernel(const float4* __restrict__ x4,
                     T* __restrict__ norms, T* __restrict__ cmin) {
    __shared__ T sn[64];
    int ci   = blockIdx.x;              // global chunk id (b*64 + c)
    int wave = threadIdx.x >> 6;
    int lane = threadIdx.x & 63;
    int r0   = ci * 64 + wave * 16;     // this wave's first row (16 rows/wave)

    #pragma unroll
    for (int k = 0; k < 4; ++k) {
        int rowbase = r0 + k * 4;                // 4 rows per round
        float4 p = x4[rowbase * 16 + lane];      // 64 lanes x 16B = 4 rows
        T a = (T)fabsf(p.x) + (T)fabsf(p.y) + (T)fabsf(p.z) + (T)fabsf(p.w);
        #pragma unroll
        for (int off = 8; off > 0; off >>= 1)    // reduce within 16-lane group
            a += __shfl_xor(a, off, 64);
        if ((lane & 15) == 0) {
            int r = rowbase + (lane >> 4);
            norms[r] = a;
            sn[r - ci * 64] = a;
        }
    }
    __syncthreads();
    if (threadIdx.x < 64) {                      // wave 0: min over the chunk
        T m = sn[threadIdx.x];
        #pragma unroll
        for (int off = 32; off > 0; off >>= 1) {
            T o = __shfl_xor(m, off, 64);
            m = (o < m) ? o : m;
        }
        if (threadIdx.x == 0) cmin[ci] = m;
    }
}

// ------------- Kernel B: ballot search, no LDS, 4 t's per wave -------------
template <typename T>
__global__ void __launch_bounds__(256)
tc_scan_kernel(const T* __restrict__ norms, const T* __restrict__ cmin,
               float* __restrict__ out) {
    int wave = threadIdx.x >> 6;
    int lane = threadIdx.x & 63;
    int gw   = blockIdx.x * 4 + wave;
    int t0   = gw * 4;                  // 4 consecutive t's, same chunk (4|64)
    int b    = t0 >> 12;
    int tr0  = t0 & (SS - 1);
    int c    = tr0 >> 6;
    const T* row = norms + (b << 12);

    T v  = row[(c << 6) + lane];        // current chunk        (L2)
    T cm = cmin[(b << 6) + lane];       // chunk minima, 64/row (L2, independent)

    int cached_cc = -1;
    T v2 = (T)0;
    float res[4];
    #pragma unroll
    for (int k = 0; k < 4; ++k) {
        int tr  = tr0 + k;
        int pos = tr & 63;
        T thr = (T)0.7 * (__shfl(v, pos, 64) + (T)1e-8);
        int r = 0;
        // (a) partial current chunk: j in [c*64, t)
        unsigned long long m = __ballot(lane < pos && v < thr);
        if (m) {
            r = tr - ((c << 6) + (63 - __clzll(m)));
        } else {
            // (b) nearest earlier chunk whose min qualifies
            unsigned long long mc = __ballot(lane < c && cm < thr);
            if (mc) {
                int cc = 63 - __clzll(mc);          // wave-uniform
                if (cc != cached_cc) {              // usually same for all 4 t's
                    v2 = row[(cc << 6) + lane];
                    cached_cc = cc;
                }
                // (c) nearest element within that chunk (non-empty by cmin)
                unsigned long long m2 = __ballot(v2 < thr);
                r = tr - ((cc << 6) + (63 - __clzll(m2)));
            }
        }
        res[k] = (float)r;
    }
    if (lane == 0) {
        float4 o = make_float4(res[0], res[1], res[2], res[3]);
        ((float4*)out)[gw] = o;
    }
}

extern "C" void kernel_launch(void* const* d_in, const int* in_sizes, int n_in,
                              void* d_out, int out_size, void* d_ws, size_t ws_size,
                              hipStream_t stream) {
    const float* x = (const float*)d_in[0];
    float* out = (float*)d_out;
    int total  = in_sizes[0];           // B*S*D = 1048576
    int nrows  = total / DD;            // B*S   = 16384
    int nchunk = nrows / 64;            // 256

    int grdA = nchunk;                  // 256 blocks, 64 rows each
    int grdB = nrows / 16;              // 1024 blocks: 4 waves x 4 t's

    // f64 norms/compares: a flip near the 0.7 threshold changes tc by O(S)
    // >> absmax tolerance; f64 margins ~1e-13. (R1/R2: absmax 0.)
    if (ws_size >= (size_t)(nrows + nchunk) * sizeof(double)) {
        double* nrm = (double*)d_ws;
        double* cmn = nrm + nrows;
        tc_norms_cmin_kernel<double><<<grdA, 256, 0, stream>>>((const float4*)x, nrm, cmn);
        tc_scan_kernel<double><<<grdB, 256, 0, stream>>>(nrm, cmn, out);
    } else {
        float* nrm = (float*)d_ws;
        float* cmn = nrm + nrows;
        tc_norms_cmin_kernel<float><<<grdA, 256, 0, stream>>>((const float4*)x, nrm, cmn);
        tc_scan_kernel<float><<<grdB, 256, 0, stream>>>(nrm, cmn, out);
    }
}